// Round 12
// baseline (1076.096 us; speedup 1.0000x reference)
//
#include <hip/hip_runtime.h>
#include <math.h>

// Fixed shapes: b_edges (64,1,512,512) f32, sobel (64,2,512,512) f32
// BASE=256, PY_SIZES=[256,64]
// SINGLE fused kernel, 1024 blocks x 256 threads, ALL co-resident
// (__launch_bounds__(256,4) caps VGPRs at 128 -> 4 blocks/CU x 256 CUs).
// Block = 4 waves; wave w owns group g = blk*4+w (= b*64+R): output rows
// 4R..4R+3, lane X owns cols 4X..4X+3 (one level-1 cell).
// Phase A: E-pass -> pred (kept in REGISTERS), counts -> done-counter.
// Phase B: the last-arriving block scans counts -> offs/totals, sets flag
//          (runs hidden under other blocks' S-loads).
// Phase C: S-loads + compute immediately (no wait); poll flag only right
//          before the stores. No grid barrier, no pred16 round-trip.
// 512->256 align-corners: pos(i)=i*511/255 (exact f32 product, IEEE div),
// lo(i)=2i, w=pos-2i (i=255 -> w=1.0, bit-identical to the lo=hi=511 form).

typedef unsigned long long u64;
#define OFFSET1 4194304   // lin_id offset of level 1 (=64*256*256)

__device__ __forceinline__ int aload(const int* p) {
    return __hip_atomic_load(p, __ATOMIC_RELAXED, __HIP_MEMORY_SCOPE_AGENT);
}
__device__ __forceinline__ void astore(int* p, int v) {
    __hip_atomic_store(p, v, __ATOMIC_RELAXED, __HIP_MEMORY_SCOPE_AGENT);
}

__device__ __forceinline__ void write_row(float* __restrict__ out, int N, int row,
                                          float cy, float cx, float s0v, float s1v,
                                          float half, float sz, float imgid,
                                          float prow, float mylin) {
    float len = sqrtf(s0v * s0v + s1v * s1v);
    float n0 = s0v / len, n1 = s1v / len;
    float rt0 = n1 * half, rt1 = -n0 * half;
    ((float2*)out)[row]           = make_float2(cy + rt0, cx + rt1);  // locs_lf
    ((float2*)(out + 2 * N))[row] = make_float2(cy - rt0, cx - rt1);  // locs_rt
    ((float2*)(out + 4 * N))[row] = make_float2(n0, n1);              // norms
    out[6 * N + row] = sz;                                            // sizes
    ((float2*)(out + 7 * N))[row] = make_float2(cy, cx);              // centers
    out[9 * N + row] = imgid;                                         // imgid
    out[10 * N + row] = prow;                                         // p_rowids
    out[11 * N + row] = mylin;                                        // my_lin
}

__global__ __launch_bounds__(256, 4) void fused_kernel(
        const float* __restrict__ E, const float* __restrict__ S,
        int* __restrict__ counts0, int* __restrict__ counts1,
        int* __restrict__ offs0, int* __restrict__ offs1,
        int* __restrict__ totals, int* __restrict__ syn,
        float* __restrict__ out, int N) {
    int tid = threadIdx.x, lane = tid & 63, wave = tid >> 6;
    int g = blockIdx.x * 4 + wave;                   // 0..4095
    int bimg = g >> 6, R = g & 63;

    float wx[4], cwx[4];
    #pragma unroll
    for (int j = 0; j < 4; ++j) {
        int xi = 4 * lane + j;
        wx[j] = (float)(xi * 511) / 255.0f - (float)(8 * lane + 2 * j);
        cwx[j] = 1.0f - wx[j];
    }

    // ---------------- phase A: E-pass (pred stays in registers) -------------
    unsigned pred = 0;
    int rc0 = 0;
    {
        const float* Ep = E + bimg * 262144 + (8 * R) * 512 + 8 * lane;
        float4 L[8], H[8];
        #pragma unroll
        for (int k = 0; k < 8; ++k) {
            L[k] = *(const float4*)(Ep + k * 512);
            H[k] = *(const float4*)(Ep + k * 512 + 4);
        }
        #pragma unroll
        for (int r = 0; r < 4; ++r) {
            int y = 4 * R + r;
            float wy = (float)(y * 511) / 255.0f - (float)(2 * y);
            float cwy = 1.0f - wy;
            float4 lo = L[2 * r], loh = H[2 * r];
            float4 hi = L[2 * r + 1], hih = H[2 * r + 1];
            float e0 = (lo.x*cwy + hi.x*wy)*cwx[0] + (lo.y*cwy + hi.y*wy)*wx[0];
            float e1 = (lo.z*cwy + hi.z*wy)*cwx[1] + (lo.w*cwy + hi.w*wy)*wx[1];
            float e2 = (loh.x*cwy + hih.x*wy)*cwx[2] + (loh.y*cwy + hih.y*wy)*wx[2];
            float e3 = (loh.z*cwy + hih.z*wy)*cwx[3] + (loh.w*cwy + hih.w*wy)*wx[3];
            pred |= (e0 != 0.0f ? 1u : 0u) << (4*r+0);
            pred |= (e1 != 0.0f ? 1u : 0u) << (4*r+1);
            pred |= (e2 != 0.0f ? 1u : 0u) << (4*r+2);
            pred |= (e3 != 0.0f ? 1u : 0u) << (4*r+3);
            u64 b0 = __ballot(e0 != 0.0f), b1 = __ballot(e1 != 0.0f);
            u64 b2 = __ballot(e2 != 0.0f), b3 = __ballot(e3 != 0.0f);
            rc0 += __popcll(b0) + __popcll(b1) + __popcll(b2) + __popcll(b3);
        }
    }
    u64 m1 = __ballot(pred != 0);
    if (lane == 0) {
        astore(&counts0[g], rc0);
        astore(&counts1[g], __popcll(m1));
    }
    __syncthreads();
    __shared__ int is_scanner;
    if (tid == 0) {
        __threadfence();
        int old = __hip_atomic_fetch_add(&syn[0], 1, __ATOMIC_ACQ_REL,
                                         __HIP_MEMORY_SCOPE_AGENT);
        is_scanner = (old == (int)gridDim.x - 1);
    }
    __syncthreads();

    // ---------------- phase B: last-arriving block scans --------------------
    if (is_scanner) {
        __shared__ int wsum[4];
        int carry = 0;
        for (int base = 0; base < 4096; base += 256) {
            int v = aload(&counts0[base + tid]);
            int inc = v;
            #pragma unroll
            for (int d = 1; d < 64; d <<= 1) {
                int t = __shfl_up(inc, (unsigned)d, 64);
                if (lane >= d) inc += t;
            }
            if (lane == 63) wsum[wave] = inc;
            __syncthreads();
            int wbase = 0;
            for (int i = 0; i < wave; ++i) wbase += wsum[i];
            int tot = wsum[0] + wsum[1] + wsum[2] + wsum[3];
            astore(&offs0[base + tid], carry + wbase + inc - v);
            carry += tot;
            __syncthreads();
        }
        if (tid == 0) astore(&totals[0], carry);
        int carry1 = 0;
        for (int base = 0; base < 4096; base += 256) {
            int v = aload(&counts1[base + tid]);
            int inc = v;
            #pragma unroll
            for (int d = 1; d < 64; d <<= 1) {
                int t = __shfl_up(inc, (unsigned)d, 64);
                if (lane >= d) inc += t;
            }
            if (lane == 63) wsum[wave] = inc;
            __syncthreads();
            int wbase = 0;
            for (int i = 0; i < wave; ++i) wbase += wsum[i];
            int tot = wsum[0] + wsum[1] + wsum[2] + wsum[3];
            astore(&offs1[base + tid], carry1 + wbase + inc - v);
            carry1 += tot;
            __syncthreads();
        }
        if (tid == 0) {
            __threadfence();
            __hip_atomic_store(&syn[1], 1, __ATOMIC_RELEASE,
                               __HIP_MEMORY_SCOPE_AGENT);
        }
    }

    // ---------------- phase C: S-pass -------------------------------------
    const float* Sa = S + (size_t)(2 * bimg) * 262144 + (8 * R) * 512 + 8 * lane;
    const float* Sq = Sa + 262144;

    // issue first-half loads, then poll the scan flag (latency overlaps spin)
    float4 A[4], Ax[4], Q[4], Qx[4];
    #pragma unroll
    for (int k = 0; k < 4; ++k) {
        A[k]  = *(const float4*)(Sa + k * 512);
        Ax[k] = *(const float4*)(Sa + k * 512 + 4);
        Q[k]  = *(const float4*)(Sq + k * 512);
        Qx[k] = *(const float4*)(Sq + k * 512 + 4);
    }

    {
        int guard = 0;
        while (__hip_atomic_load(&syn[1], __ATOMIC_ACQUIRE,
                                 __HIP_MEMORY_SCOPE_AGENT) == 0) {
            __builtin_amdgcn_s_sleep(8);
            if (++guard > (1 << 22)) break;   // safety valve
        }
    }
    int base0 = aload(&offs0[g]);
    int prow = aload(&totals[0]) + aload(&offs1[g]) +
               __popcll(m1 & ((1ull << lane) - 1ull));

    float acc0 = 0.0f, acc1 = 0.0f;
    int rc = 0;
    #pragma unroll
    for (int h = 0; h < 2; ++h) {
        if (h == 1) {   // second-half loads
            #pragma unroll
            for (int k = 0; k < 4; ++k) {
                A[k]  = *(const float4*)(Sa + (4 + k) * 512);
                Ax[k] = *(const float4*)(Sa + (4 + k) * 512 + 4);
                Q[k]  = *(const float4*)(Sq + (4 + k) * 512);
                Qx[k] = *(const float4*)(Sq + (4 + k) * 512 + 4);
            }
        }
        #pragma unroll
        for (int rr = 0; rr < 2; ++rr) {
            int r = 2 * h + rr;
            int y = 4 * R + r;
            float wy = (float)(y * 511) / 255.0f - (float)(2 * y);
            float cwy = 1.0f - wy;
            float4 lo = A[2*rr], loh = Ax[2*rr], hi = A[2*rr+1], hih = Ax[2*rr+1];
            float4 ql = Q[2*rr], qlh = Qx[2*rr], qh = Q[2*rr+1], qhh = Qx[2*rr+1];
            float va[4], vb[4];
            va[0] = (lo.x*cwy + hi.x*wy)*cwx[0] + (lo.y*cwy + hi.y*wy)*wx[0];
            va[1] = (lo.z*cwy + hi.z*wy)*cwx[1] + (lo.w*cwy + hi.w*wy)*wx[1];
            va[2] = (loh.x*cwy + hih.x*wy)*cwx[2] + (loh.y*cwy + hih.y*wy)*wx[2];
            va[3] = (loh.z*cwy + hih.z*wy)*cwx[3] + (loh.w*cwy + hih.w*wy)*wx[3];
            vb[0] = (ql.x*cwy + qh.x*wy)*cwx[0] + (ql.y*cwy + qh.y*wy)*wx[0];
            vb[1] = (ql.z*cwy + qh.z*wy)*cwx[1] + (ql.w*cwy + qh.w*wy)*wx[1];
            vb[2] = (qlh.x*cwy + qhh.x*wy)*cwx[2] + (qlh.y*cwy + qhh.y*wy)*wx[2];
            vb[3] = (qlh.z*cwy + qhh.z*wy)*cwx[3] + (qlh.w*cwy + qhh.w*wy)*wx[3];
            acc0 += va[0] + va[1] + va[2] + va[3];
            acc1 += vb[0] + vb[1] + vb[2] + vb[3];

            unsigned pr = (pred >> (4 * r)) & 0xF;
            u64 b0 = __ballot((pr & 1) != 0);
            u64 b1 = __ballot((pr & 2) != 0);
            u64 b2 = __ballot((pr & 4) != 0);
            u64 b3 = __ballot((pr & 8) != 0);
            u64 ltm = (1ull << lane) - 1ull;
            int pre = __popcll(b0 & ltm) + __popcll(b1 & ltm) +
                      __popcll(b2 & ltm) + __popcll(b3 & ltm);
            int rbase = base0 + rc + pre;
            int own = 0;
            #pragma unroll
            for (int j = 0; j < 4; ++j) {
                if (pr & (1u << j)) {
                    int row = rbase + own;
                    own++;
                    int x = 4 * lane + j;
                    float cy = (float)y + 0.5f, cx = (float)x + 0.5f;
                    write_row(out, N, row, cy, cx, va[j], vb[j], 0.5f, 1.0f,
                              (float)bimg, (float)prow,
                              (float)((bimg << 16) + (y << 8) + x));
                }
            }
            rc += __popcll(b0) + __popcll(b1) + __popcll(b2) + __popcll(b3);
        }
    }

    // level-1 row for this lane's cell
    if (pred != 0) {
        float v0 = acc0 * (1.0f / 16.0f), v1 = acc1 * (1.0f / 16.0f);
        float cy = ((float)R + 0.5f) * 4.0f, cx = ((float)lane + 0.5f) * 4.0f;
        write_row(out, N, prow, cy, cx, v0, v1, 2.0f, 4.0f, (float)bimg,
                  (float)prow, (float)(OFFSET1 + g * 64 + lane));
    }
}

extern "C" void kernel_launch(void* const* d_in, const int* in_sizes, int n_in,
                              void* d_out, int out_size, void* d_ws, size_t ws_size,
                              hipStream_t stream) {
    const float* E = (const float*)d_in[0];   // b_edges (64,1,512,512)
    const float* S = (const float*)d_in[1];   // sobel   (64,2,512,512)
    float* out = (float*)d_out;
    int N = out_size / 12;                    // 8 outputs = 12 floats/row

    // workspace (ints): counts0[4096] counts1[4096] offs0[4096] offs1[4096]
    //                   totals[2] syn[2]
    int* ws = (int*)d_ws;
    int* counts0 = ws;
    int* counts1 = counts0 + 4096;
    int* offs0   = counts1 + 4096;
    int* offs1   = offs0 + 4096;
    int* totals  = offs1 + 4096;
    int* syn     = totals + 2;

    hipMemsetAsync(syn, 0, 2 * sizeof(int), stream);
    fused_kernel<<<1024, 256, 0, stream>>>(E, S, counts0, counts1,
                                           offs0, offs1, totals, syn, out, N);
}

// Round 13
// 152.702 us; speedup vs baseline: 7.0470x; 7.0470x over previous
//
#include <hip/hip_runtime.h>
#include <math.h>

// Fixed shapes: b_edges (64,1,512,512) f32, sobel (64,2,512,512) f32
// BASE=256, PY_SIZES=[256,64]
// Round-6 structure with scan FOLDED into prepE as a last-arriving-block
// epilogue (no polling: non-scanner blocks exit; the dispatch boundary to
// prepS is the dependency). Counts/offs go through device-scope atomics
// (cross-XCD L2s are not coherent; pattern correctness-proven in R12).
// Group g = b*64 + R owns output rows 4R..4R+3 (input rows 8R..8R+7).
// prepE: one wave per group; lane X owns cols 4X..4X+3 == one level-1 cell.
// prepS: one wave per group; reads S only; writes all output rows directly.
// 512->256 align-corners: pos(i)=i*511/255 (exact f32 product, IEEE div),
// lo(i)=2i, w=pos-2i (i=255 -> w=1.0, bit-identical to the lo=hi=511 form).

typedef unsigned long long u64;
#define OFFSET1 4194304   // lin_id offset of level 1 (=64*256*256)

__device__ __forceinline__ int aload(const int* p) {
    return __hip_atomic_load(p, __ATOMIC_RELAXED, __HIP_MEMORY_SCOPE_AGENT);
}
__device__ __forceinline__ void astore(int* p, int v) {
    __hip_atomic_store(p, v, __ATOMIC_RELAXED, __HIP_MEMORY_SCOPE_AGENT);
}

// ---------------------------------------------------------------------------
// prepE+scan: E-only pass; the LAST block to finish scans counts -> offs.
// ---------------------------------------------------------------------------
__global__ __launch_bounds__(256) void prepE_kernel(const float* __restrict__ E,
                                                    unsigned short* __restrict__ pred16,
                                                    u64* __restrict__ mask1,
                                                    int* __restrict__ counts0,
                                                    int* __restrict__ counts1,
                                                    int* __restrict__ offs0,
                                                    int* __restrict__ offs1,
                                                    int* __restrict__ totals,
                                                    int* __restrict__ syn) {
    int tid = threadIdx.x;
    int lane = tid & 63, wave = tid >> 6;
    int g = blockIdx.x * 4 + wave;                   // 0..4095
    int b = g >> 6, R = g & 63;

    const float* Ep = E + b * 262144 + (8 * R) * 512 + 8 * lane;
    float4 L[8], H[8];
    #pragma unroll
    for (int k = 0; k < 8; ++k) {
        L[k] = *(const float4*)(Ep + k * 512);
        H[k] = *(const float4*)(Ep + k * 512 + 4);
    }

    float wx[4], cwx[4];
    #pragma unroll
    for (int j = 0; j < 4; ++j) {
        int xi = 4 * lane + j;
        wx[j] = (float)(xi * 511) / 255.0f - (float)(8 * lane + 2 * j);
        cwx[j] = 1.0f - wx[j];
    }

    unsigned pred = 0;
    int rc = 0;
    #pragma unroll
    for (int r = 0; r < 4; ++r) {
        int y = 4 * R + r;
        float wy = (float)(y * 511) / 255.0f - (float)(2 * y);
        float cwy = 1.0f - wy;
        float4 lo = L[2 * r], loh = H[2 * r];
        float4 hi = L[2 * r + 1], hih = H[2 * r + 1];
        float e0 = (lo.x*cwy + hi.x*wy)*cwx[0] + (lo.y*cwy + hi.y*wy)*wx[0];
        float e1 = (lo.z*cwy + hi.z*wy)*cwx[1] + (lo.w*cwy + hi.w*wy)*wx[1];
        float e2 = (loh.x*cwy + hih.x*wy)*cwx[2] + (loh.y*cwy + hih.y*wy)*wx[2];
        float e3 = (loh.z*cwy + hih.z*wy)*cwx[3] + (loh.w*cwy + hih.w*wy)*wx[3];
        bool p0 = (e0 != 0.0f), p1 = (e1 != 0.0f), p2 = (e2 != 0.0f), p3 = (e3 != 0.0f);
        pred |= (p0?1u:0u) << (4*r+0);
        pred |= (p1?1u:0u) << (4*r+1);
        pred |= (p2?1u:0u) << (4*r+2);
        pred |= (p3?1u:0u) << (4*r+3);
        u64 b0 = __ballot(p0), b1 = __ballot(p1), b2 = __ballot(p2), b3 = __ballot(p3);
        rc += __popcll(b0) + __popcll(b1) + __popcll(b2) + __popcll(b3);
    }
    u64 m1 = __ballot(pred != 0);
    pred16[g * 64 + lane] = (unsigned short)pred;
    if (lane == 0) {
        astore(&counts0[g], rc);
        astore(&counts1[g], __popcll(m1));
        mask1[g] = m1;
    }

    // -------- last-arriving block performs the scan (no other block waits) --
    __syncthreads();
    __shared__ int is_scanner;
    if (tid == 0) {
        __threadfence();
        int old = __hip_atomic_fetch_add(&syn[0], 1, __ATOMIC_ACQ_REL,
                                         __HIP_MEMORY_SCOPE_AGENT);
        is_scanner = (old == (int)gridDim.x - 1);
    }
    __syncthreads();
    if (!is_scanner) return;

    __shared__ int wsum[4];
    int carry = 0;
    for (int base = 0; base < 4096; base += 256) {
        int v = aload(&counts0[base + tid]);
        int inc = v;
        #pragma unroll
        for (int d = 1; d < 64; d <<= 1) {
            int t = __shfl_up(inc, (unsigned)d, 64);
            if (lane >= d) inc += t;
        }
        if (lane == 63) wsum[wave] = inc;
        __syncthreads();
        int wbase = 0;
        for (int i = 0; i < wave; ++i) wbase += wsum[i];
        int tot = wsum[0] + wsum[1] + wsum[2] + wsum[3];
        astore(&offs0[base + tid], carry + wbase + inc - v);
        carry += tot;
        __syncthreads();
    }
    if (tid == 0) astore(&totals[0], carry);
    int carry1 = 0;
    for (int base = 0; base < 4096; base += 256) {
        int v = aload(&counts1[base + tid]);
        int inc = v;
        #pragma unroll
        for (int d = 1; d < 64; d <<= 1) {
            int t = __shfl_up(inc, (unsigned)d, 64);
            if (lane >= d) inc += t;
        }
        if (lane == 63) wsum[wave] = inc;
        __syncthreads();
        int wbase = 0;
        for (int i = 0; i < wave; ++i) wbase += wsum[i];
        int tot = wsum[0] + wsum[1] + wsum[2] + wsum[3];
        astore(&offs1[base + tid], carry1 + wbase + inc - v);
        carry1 += tot;
        __syncthreads();
    }
    if (tid == 0) astore(&totals[1], carry1);
}

__device__ __forceinline__ void write_row(float* __restrict__ out, int N, int row,
                                          float cy, float cx, float s0v, float s1v,
                                          float half, float sz, float imgid,
                                          float prow, float mylin) {
    float len = sqrtf(s0v * s0v + s1v * s1v);
    float n0 = s0v / len, n1 = s1v / len;
    float rt0 = n1 * half, rt1 = -n0 * half;
    ((float2*)out)[row]           = make_float2(cy + rt0, cx + rt1);  // locs_lf
    ((float2*)(out + 2 * N))[row] = make_float2(cy - rt0, cx - rt1);  // locs_rt
    ((float2*)(out + 4 * N))[row] = make_float2(n0, n1);              // norms
    out[6 * N + row] = sz;                                            // sizes
    ((float2*)(out + 7 * N))[row] = make_float2(cy, cx);              // centers
    out[9 * N + row] = imgid;                                         // imgid
    out[10 * N + row] = prow;                                         // p_rowids
    out[11 * N + row] = mylin;                                        // my_lin
}

// ---------------------------------------------------------------------------
// prepS: S-only pass + ALL output writes. Ranks recomputed in-wave from
// pred16 via ballots; parent row is register-local (lane owns the L1 cell).
// ---------------------------------------------------------------------------
__global__ __launch_bounds__(256) void prepS_kernel(const float* __restrict__ S,
                                                    const unsigned short* __restrict__ pred16,
                                                    const u64* __restrict__ mask1,
                                                    const int* __restrict__ offs0,
                                                    const int* __restrict__ offs1,
                                                    const int* __restrict__ totals,
                                                    float* __restrict__ out, int N) {
    int lane = threadIdx.x & 63;
    int g = blockIdx.x * 4 + (threadIdx.x >> 6);     // 0..4095
    int bimg = g >> 6, R = g & 63;

    u64 m1 = mask1[g];
    if (m1 == 0ull) return;                          // wave-uniform: nothing active
    unsigned pred = pred16[g * 64 + lane];
    int base0 = aload(&offs0[g]);
    int prow = aload(&totals[0]) + aload(&offs1[g]) +
               __popcll(m1 & ((1ull << lane) - 1ull));

    float wx[4], cwx[4];
    #pragma unroll
    for (int j = 0; j < 4; ++j) {
        int xi = 4 * lane + j;
        wx[j] = (float)(xi * 511) / 255.0f - (float)(8 * lane + 2 * j);
        cwx[j] = 1.0f - wx[j];
    }

    const float* Sa = S + (size_t)(2 * bimg) * 262144 + (8 * R) * 512 + 8 * lane;
    const float* Sq = Sa + 262144;

    float acc0 = 0.0f, acc1 = 0.0f;
    int rc = 0;
    #pragma unroll
    for (int h = 0; h < 2; ++h) {                    // two halves: rows 4h..4h+3
        float4 A[4], Ax[4], Q[4], Qx[4];
        #pragma unroll
        for (int k = 0; k < 4; ++k) {
            const float* pa = Sa + (4 * h + k) * 512;
            A[k]  = *(const float4*)pa;
            Ax[k] = *(const float4*)(pa + 4);
            const float* pq = Sq + (4 * h + k) * 512;
            Q[k]  = *(const float4*)pq;
            Qx[k] = *(const float4*)(pq + 4);
        }
        #pragma unroll
        for (int rr = 0; rr < 2; ++rr) {
            int r = 2 * h + rr;
            int y = 4 * R + r;
            float wy = (float)(y * 511) / 255.0f - (float)(2 * y);
            float cwy = 1.0f - wy;
            float4 lo = A[2*rr], loh = Ax[2*rr], hi = A[2*rr+1], hih = Ax[2*rr+1];
            float4 ql = Q[2*rr], qlh = Qx[2*rr], qh = Q[2*rr+1], qhh = Qx[2*rr+1];
            float va[4], vb[4];
            va[0] = (lo.x*cwy + hi.x*wy)*cwx[0] + (lo.y*cwy + hi.y*wy)*wx[0];
            va[1] = (lo.z*cwy + hi.z*wy)*cwx[1] + (lo.w*cwy + hi.w*wy)*wx[1];
            va[2] = (loh.x*cwy + hih.x*wy)*cwx[2] + (loh.y*cwy + hih.y*wy)*wx[2];
            va[3] = (loh.z*cwy + hih.z*wy)*cwx[3] + (loh.w*cwy + hih.w*wy)*wx[3];
            vb[0] = (ql.x*cwy + qh.x*wy)*cwx[0] + (ql.y*cwy + qh.y*wy)*wx[0];
            vb[1] = (ql.z*cwy + qh.z*wy)*cwx[1] + (ql.w*cwy + qh.w*wy)*wx[1];
            vb[2] = (qlh.x*cwy + qhh.x*wy)*cwx[2] + (qlh.y*cwy + qhh.y*wy)*wx[2];
            vb[3] = (qlh.z*cwy + qhh.z*wy)*cwx[3] + (qlh.w*cwy + qhh.w*wy)*wx[3];
            acc0 += va[0] + va[1] + va[2] + va[3];
            acc1 += vb[0] + vb[1] + vb[2] + vb[3];

            unsigned pr = (pred >> (4 * r)) & 0xF;
            u64 b0 = __ballot((pr & 1) != 0);
            u64 b1 = __ballot((pr & 2) != 0);
            u64 b2 = __ballot((pr & 4) != 0);
            u64 b3 = __ballot((pr & 8) != 0);
            u64 ltm = (1ull << lane) - 1ull;
            int pre = __popcll(b0 & ltm) + __popcll(b1 & ltm) +
                      __popcll(b2 & ltm) + __popcll(b3 & ltm);
            int rbase = base0 + rc + pre;
            int own = 0;
            #pragma unroll
            for (int j = 0; j < 4; ++j) {
                if (pr & (1u << j)) {
                    int row = rbase + own;
                    own++;
                    int x = 4 * lane + j;
                    float cy = (float)y + 0.5f, cx = (float)x + 0.5f;
                    write_row(out, N, row, cy, cx, va[j], vb[j], 0.5f, 1.0f,
                              (float)bimg, (float)prow,
                              (float)((bimg << 16) + (y << 8) + x));
                }
            }
            rc += __popcll(b0) + __popcll(b1) + __popcll(b2) + __popcll(b3);
        }
    }

    // level-1 row for this lane's cell
    if (pred != 0) {
        float v0 = acc0 * (1.0f / 16.0f), v1 = acc1 * (1.0f / 16.0f);
        float cy = ((float)R + 0.5f) * 4.0f, cx = ((float)lane + 0.5f) * 4.0f;
        write_row(out, N, prow, cy, cx, v0, v1, 2.0f, 4.0f, (float)bimg,
                  (float)prow, (float)(OFFSET1 + g * 64 + lane));
    }
}

extern "C" void kernel_launch(void* const* d_in, const int* in_sizes, int n_in,
                              void* d_out, int out_size, void* d_ws, size_t ws_size,
                              hipStream_t stream) {
    const float* E = (const float*)d_in[0];   // b_edges (64,1,512,512)
    const float* S = (const float*)d_in[1];   // sobel   (64,2,512,512)
    float* out = (float*)d_out;
    int N = out_size / 12;                    // 8 outputs = 12 floats/row

    // workspace layout (byte offsets); ~622 KB total
    char* ws = (char*)d_ws;
    int* counts0 = (int*)(ws + 0);            // 4096 ints
    int* offs0   = (int*)(ws + 16384);        // 4096
    int* counts1 = (int*)(ws + 32768);        // 4096
    int* offs1   = (int*)(ws + 49152);        // 4096
    int* totals  = (int*)(ws + 65536);        // 2
    int* syn     = (int*)(ws + 65544);        // 1 (arrival counter)
    u64* mask1   = (u64*)(ws + 65600);        // 4096 u64 = 32 KB (8B aligned)
    unsigned short* pred16 = (unsigned short*)(ws + 98368);  // 512 KB

    hipMemsetAsync(syn, 0, sizeof(int), stream);
    prepE_kernel<<<1024, 256, 0, stream>>>(E, pred16, mask1, counts0, counts1,
                                           offs0, offs1, totals, syn);
    prepS_kernel<<<1024, 256, 0, stream>>>(S, pred16, mask1, offs0, offs1,
                                           totals, out, N);
}

// Round 14
// 78.326 us; speedup vs baseline: 13.7387x; 1.9496x over previous
//
#include <hip/hip_runtime.h>
#include <math.h>

// Fixed shapes: b_edges (64,1,512,512) f32, sobel (64,2,512,512) f32
// BASE=256, PY_SIZES=[256,64]
// FINAL structure (best measured: 75.9 us, round 6):
//   prepE (E-only read pass) -> scan (tiny) -> prepS (S read + all writes).
// No device-scope sync anywhere (R4/R12/R13 showed any grid self-sync or
// fence-per-block costs 50-1000 us on this chip); kernel boundaries provide
// the dependencies. Mixed read+write streams measure ~3.5 TB/s on gfx950 vs
// 5.4-7.1 TB/s pure-direction; with ~267 MB compulsory traffic this is the
// achievable plateau.
// Group g = b*64 + R owns output rows 4R..4R+3 (input rows 8R..8R+7).
// prepE: one wave per group; lane X owns cols 4X..4X+3 == one level-1 cell.
// prepS: one wave per group; reads S only; writes all output rows directly.
// 512->256 align-corners: pos(i)=i*511/255 (exact f32 product, IEEE div),
// lo(i)=2i, w=pos-2i (i=255 -> w=1.0, bit-identical to the lo=hi=511 form).

typedef unsigned long long u64;
#define OFFSET1 4194304   // lin_id offset of level 1 (=64*256*256)

// ---------------------------------------------------------------------------
// prepE: E-only pass. 16 upfront float4 loads per lane, predicates for the
// lane's 16 pixels, ballots -> counts + masks.
// ---------------------------------------------------------------------------
__global__ __launch_bounds__(256) void prepE_kernel(const float* __restrict__ E,
                                                    unsigned short* __restrict__ pred16,
                                                    u64* __restrict__ mask1,
                                                    int* __restrict__ counts0,
                                                    int* __restrict__ counts1) {
    int lane = threadIdx.x & 63;
    int g = blockIdx.x * 4 + (threadIdx.x >> 6);     // 0..4095
    int b = g >> 6, R = g & 63;

    const float* Ep = E + b * 262144 + (8 * R) * 512 + 8 * lane;
    float4 L[8], H[8];
    #pragma unroll
    for (int k = 0; k < 8; ++k) {
        L[k] = *(const float4*)(Ep + k * 512);
        H[k] = *(const float4*)(Ep + k * 512 + 4);
    }

    float wx[4], cwx[4];
    #pragma unroll
    for (int j = 0; j < 4; ++j) {
        int xi = 4 * lane + j;
        wx[j] = (float)(xi * 511) / 255.0f - (float)(8 * lane + 2 * j);
        cwx[j] = 1.0f - wx[j];
    }

    unsigned pred = 0;
    int rc = 0;
    #pragma unroll
    for (int r = 0; r < 4; ++r) {
        int y = 4 * R + r;
        float wy = (float)(y * 511) / 255.0f - (float)(2 * y);
        float cwy = 1.0f - wy;
        float4 lo = L[2 * r], loh = H[2 * r];
        float4 hi = L[2 * r + 1], hih = H[2 * r + 1];
        float e0 = (lo.x*cwy + hi.x*wy)*cwx[0] + (lo.y*cwy + hi.y*wy)*wx[0];
        float e1 = (lo.z*cwy + hi.z*wy)*cwx[1] + (lo.w*cwy + hi.w*wy)*wx[1];
        float e2 = (loh.x*cwy + hih.x*wy)*cwx[2] + (loh.y*cwy + hih.y*wy)*wx[2];
        float e3 = (loh.z*cwy + hih.z*wy)*cwx[3] + (loh.w*cwy + hih.w*wy)*wx[3];
        bool p0 = (e0 != 0.0f), p1 = (e1 != 0.0f), p2 = (e2 != 0.0f), p3 = (e3 != 0.0f);
        pred |= (p0?1u:0u) << (4*r+0);
        pred |= (p1?1u:0u) << (4*r+1);
        pred |= (p2?1u:0u) << (4*r+2);
        pred |= (p3?1u:0u) << (4*r+3);
        u64 b0 = __ballot(p0), b1 = __ballot(p1), b2 = __ballot(p2), b3 = __ballot(p3);
        rc += __popcll(b0) + __popcll(b1) + __popcll(b2) + __popcll(b3);
    }
    u64 m1 = __ballot(pred != 0);
    pred16[g * 64 + lane] = (unsigned short)pred;
    if (lane == 0) {
        counts0[g] = rc;
        counts1[g] = __popcll(m1);
        mask1[g] = m1;
    }
}

// single-block exclusive scan of counts0[4096] and counts1[4096]
__global__ __launch_bounds__(1024) void scan_kernel(const int* __restrict__ counts0,
                                                    int* __restrict__ offs0,
                                                    const int* __restrict__ counts1,
                                                    int* __restrict__ offs1,
                                                    int* __restrict__ totals) {
    __shared__ int wsum[16];
    int tid = threadIdx.x, lane = tid & 63, wave = tid >> 6;

    int carry = 0;
    for (int base = 0; base < 4096; base += 1024) {
        int v = counts0[base + tid];
        int inc = v;
        #pragma unroll
        for (int d = 1; d < 64; d <<= 1) {
            int t = __shfl_up(inc, (unsigned)d, 64);
            if (lane >= d) inc += t;
        }
        if (lane == 63) wsum[wave] = inc;
        __syncthreads();
        int wbase = 0;
        for (int i = 0; i < wave; ++i) wbase += wsum[i];
        int tot = 0;
        #pragma unroll
        for (int i = 0; i < 16; ++i) tot += wsum[i];
        offs0[base + tid] = carry + wbase + inc - v;
        carry += tot;
        __syncthreads();
    }
    if (tid == 0) totals[0] = carry;

    int carry1 = 0;
    for (int base = 0; base < 4096; base += 1024) {
        int v = counts1[base + tid];
        int inc = v;
        #pragma unroll
        for (int d = 1; d < 64; d <<= 1) {
            int t = __shfl_up(inc, (unsigned)d, 64);
            if (lane >= d) inc += t;
        }
        if (lane == 63) wsum[wave] = inc;
        __syncthreads();
        int wbase = 0;
        for (int i = 0; i < wave; ++i) wbase += wsum[i];
        int tot = 0;
        #pragma unroll
        for (int i = 0; i < 16; ++i) tot += wsum[i];
        offs1[base + tid] = carry1 + wbase + inc - v;
        carry1 += tot;
        __syncthreads();
    }
    if (tid == 0) totals[1] = carry1;
}

__device__ __forceinline__ void write_row(float* __restrict__ out, int N, int row,
                                          float cy, float cx, float s0v, float s1v,
                                          float half, float sz, float imgid,
                                          float prow, float mylin) {
    float len = sqrtf(s0v * s0v + s1v * s1v);
    float n0 = s0v / len, n1 = s1v / len;
    float rt0 = n1 * half, rt1 = -n0 * half;
    ((float2*)out)[row]           = make_float2(cy + rt0, cx + rt1);  // locs_lf
    ((float2*)(out + 2 * N))[row] = make_float2(cy - rt0, cx - rt1);  // locs_rt
    ((float2*)(out + 4 * N))[row] = make_float2(n0, n1);              // norms
    out[6 * N + row] = sz;                                            // sizes
    ((float2*)(out + 7 * N))[row] = make_float2(cy, cx);              // centers
    out[9 * N + row] = imgid;                                         // imgid
    out[10 * N + row] = prow;                                         // p_rowids
    out[11 * N + row] = mylin;                                        // my_lin
}

// ---------------------------------------------------------------------------
// prepS: S-only pass + ALL output writes. Ranks recomputed in-wave from
// pred16 via ballots; parent row is register-local (lane owns the L1 cell).
// ---------------------------------------------------------------------------
__global__ __launch_bounds__(256) void prepS_kernel(const float* __restrict__ S,
                                                    const unsigned short* __restrict__ pred16,
                                                    const u64* __restrict__ mask1,
                                                    const int* __restrict__ offs0,
                                                    const int* __restrict__ offs1,
                                                    const int* __restrict__ totals,
                                                    float* __restrict__ out, int N) {
    int lane = threadIdx.x & 63;
    int g = blockIdx.x * 4 + (threadIdx.x >> 6);     // 0..4095
    int bimg = g >> 6, R = g & 63;

    u64 m1 = mask1[g];
    if (m1 == 0ull) return;                          // wave-uniform: nothing active
    unsigned pred = pred16[g * 64 + lane];
    int base0 = offs0[g];
    int prow = totals[0] + offs1[g] + __popcll(m1 & ((1ull << lane) - 1ull));

    float wx[4], cwx[4];
    #pragma unroll
    for (int j = 0; j < 4; ++j) {
        int xi = 4 * lane + j;
        wx[j] = (float)(xi * 511) / 255.0f - (float)(8 * lane + 2 * j);
        cwx[j] = 1.0f - wx[j];
    }

    const float* Sa = S + (size_t)(2 * bimg) * 262144 + (8 * R) * 512 + 8 * lane;
    const float* Sq = Sa + 262144;

    float acc0 = 0.0f, acc1 = 0.0f;
    int rc = 0;
    #pragma unroll
    for (int h = 0; h < 2; ++h) {                    // two halves: rows 4h..4h+3
        float4 A[4], Ax[4], Q[4], Qx[4];
        #pragma unroll
        for (int k = 0; k < 4; ++k) {
            const float* pa = Sa + (4 * h + k) * 512;
            A[k]  = *(const float4*)pa;
            Ax[k] = *(const float4*)(pa + 4);
            const float* pq = Sq + (4 * h + k) * 512;
            Q[k]  = *(const float4*)pq;
            Qx[k] = *(const float4*)(pq + 4);
        }
        #pragma unroll
        for (int rr = 0; rr < 2; ++rr) {
            int r = 2 * h + rr;
            int y = 4 * R + r;
            float wy = (float)(y * 511) / 255.0f - (float)(2 * y);
            float cwy = 1.0f - wy;
            float4 lo = A[2*rr], loh = Ax[2*rr], hi = A[2*rr+1], hih = Ax[2*rr+1];
            float4 ql = Q[2*rr], qlh = Qx[2*rr], qh = Q[2*rr+1], qhh = Qx[2*rr+1];
            float va[4], vb[4];
            va[0] = (lo.x*cwy + hi.x*wy)*cwx[0] + (lo.y*cwy + hi.y*wy)*wx[0];
            va[1] = (lo.z*cwy + hi.z*wy)*cwx[1] + (lo.w*cwy + hi.w*wy)*wx[1];
            va[2] = (loh.x*cwy + hih.x*wy)*cwx[2] + (loh.y*cwy + hih.y*wy)*wx[2];
            va[3] = (loh.z*cwy + hih.z*wy)*cwx[3] + (loh.w*cwy + hih.w*wy)*wx[3];
            vb[0] = (ql.x*cwy + qh.x*wy)*cwx[0] + (ql.y*cwy + qh.y*wy)*wx[0];
            vb[1] = (ql.z*cwy + qh.z*wy)*cwx[1] + (ql.w*cwy + qh.w*wy)*wx[1];
            vb[2] = (qlh.x*cwy + qhh.x*wy)*cwx[2] + (qlh.y*cwy + qhh.y*wy)*wx[2];
            vb[3] = (qlh.z*cwy + qhh.z*wy)*cwx[3] + (qlh.w*cwy + qhh.w*wy)*wx[3];
            acc0 += va[0] + va[1] + va[2] + va[3];
            acc1 += vb[0] + vb[1] + vb[2] + vb[3];

            unsigned pr = (pred >> (4 * r)) & 0xF;
            u64 b0 = __ballot((pr & 1) != 0);
            u64 b1 = __ballot((pr & 2) != 0);
            u64 b2 = __ballot((pr & 4) != 0);
            u64 b3 = __ballot((pr & 8) != 0);
            u64 ltm = (1ull << lane) - 1ull;
            int pre = __popcll(b0 & ltm) + __popcll(b1 & ltm) +
                      __popcll(b2 & ltm) + __popcll(b3 & ltm);
            int rbase = base0 + rc + pre;
            int own = 0;
            #pragma unroll
            for (int j = 0; j < 4; ++j) {
                if (pr & (1u << j)) {
                    int row = rbase + own;
                    own++;
                    int x = 4 * lane + j;
                    float cy = (float)y + 0.5f, cx = (float)x + 0.5f;
                    write_row(out, N, row, cy, cx, va[j], vb[j], 0.5f, 1.0f,
                              (float)bimg, (float)prow,
                              (float)((bimg << 16) + (y << 8) + x));
                }
            }
            rc += __popcll(b0) + __popcll(b1) + __popcll(b2) + __popcll(b3);
        }
    }

    // level-1 row for this lane's cell
    if (pred != 0) {
        float v0 = acc0 * (1.0f / 16.0f), v1 = acc1 * (1.0f / 16.0f);
        float cy = ((float)R + 0.5f) * 4.0f, cx = ((float)lane + 0.5f) * 4.0f;
        write_row(out, N, prow, cy, cx, v0, v1, 2.0f, 4.0f, (float)bimg,
                  (float)prow, (float)(OFFSET1 + g * 64 + lane));
    }
}

extern "C" void kernel_launch(void* const* d_in, const int* in_sizes, int n_in,
                              void* d_out, int out_size, void* d_ws, size_t ws_size,
                              hipStream_t stream) {
    const float* E = (const float*)d_in[0];   // b_edges (64,1,512,512)
    const float* S = (const float*)d_in[1];   // sobel   (64,2,512,512)
    float* out = (float*)d_out;
    int N = out_size / 12;                    // 8 outputs = 12 floats/row

    // workspace layout (byte offsets); ~622 KB total, all written before read
    char* ws = (char*)d_ws;
    int* counts0 = (int*)(ws + 0);            // 4096 ints
    int* offs0   = (int*)(ws + 16384);        // 4096
    int* counts1 = (int*)(ws + 32768);        // 4096
    int* offs1   = (int*)(ws + 49152);        // 4096
    int* totals  = (int*)(ws + 65536);        // 2
    u64* mask1   = (u64*)(ws + 65600);        // 4096 u64 = 32 KB (8B aligned)
    unsigned short* pred16 = (unsigned short*)(ws + 98368);  // 262144 ushort = 512 KB

    prepE_kernel<<<1024, 256, 0, stream>>>(E, pred16, mask1, counts0, counts1);
    scan_kernel<<<1, 1024, 0, stream>>>(counts0, offs0, counts1, offs1, totals);
    prepS_kernel<<<1024, 256, 0, stream>>>(S, pred16, mask1, offs0, offs1,
                                           totals, out, N);
}